// Round 2
// baseline (2275.156 us; speedup 1.0000x reference)
//
#include <hip/hip_runtime.h>

// VQ-VAE fused forward, round 2: row-owned wave pipeline.
// Each wave: 16 rows. G1(x@W1^T,relu) -> h1 regs -> private LDS slice ->
// G2(h2) -> mid LDS -> G3(lat) -> mid LDS -> barrier -> G4 (wave owns 256
// protos, 2 passes x 32 rows with resident A-frags) -> argmin -> gather+loss.
// 40 KB LDS -> 4 blocks/CU. Loss finalized by last block (atomic ticket).

typedef unsigned short u16;
typedef float f32x4 __attribute__((ext_vector_type(4)));
typedef __bf16 bf16x8 __attribute__((ext_vector_type(8)));
typedef unsigned short u16x8 __attribute__((ext_vector_type(8)));
typedef unsigned short u16x4 __attribute__((ext_vector_type(4)));

#define N_ROWS 131072
#define NBLK 2048

__device__ __forceinline__ u16 f2bf(float f) {
  unsigned u = __builtin_bit_cast(unsigned, f);
  u += 0x7FFFu + ((u >> 16) & 1u);  // RTNE
  return (u16)(u >> 16);
}
__device__ __forceinline__ float bf2f(u16 h) {
  unsigned u = ((unsigned)h) << 16;
  return __builtin_bit_cast(float, u);
}
__device__ __forceinline__ f32x4 mfma16(u16x8 a, u16x8 b, f32x4 c) {
  return __builtin_amdgcn_mfma_f32_16x16x32_bf16(
      __builtin_bit_cast(bf16x8, a), __builtin_bit_cast(bf16x8, b), c, 0, 0, 0);
}
__device__ __forceinline__ u16x8 cvt8(f32x4 a, f32x4 b) {
  u16x8 h;
  h[0] = f2bf(a[0]); h[1] = f2bf(a[1]); h[2] = f2bf(a[2]); h[3] = f2bf(a[3]);
  h[4] = f2bf(b[0]); h[5] = f2bf(b[1]); h[6] = f2bf(b[2]); h[7] = f2bf(b[3]);
  return h;
}
// Swizzled LDS addressing (u16 units), 16B chunks. 2-way residual is free.
__device__ __forceinline__ int swh1(int row, int col) {  // [16][64]
  return row * 64 + ((((col >> 3) ^ (row & 7)) & 7) << 3) + (col & 7);
}
__device__ __forceinline__ int swm(int row, int col) {   // [64][256]
  return row * 256 + ((((col >> 3) ^ (row & 15)) & 31) << 3) + (col & 7);
}

// ---------------- prep: cast weights+protos to bf16, proto norms, zero accums
__global__ void prep(const float* __restrict__ W1, const float* __restrict__ W2,
                     const float* __restrict__ Wmu, const float* __restrict__ protos,
                     u16* __restrict__ w1b, u16* __restrict__ w2b,
                     u16* __restrict__ wmub, u16* __restrict__ protosb,
                     float* __restrict__ pnorm, float* __restrict__ loss_accum,
                     int* __restrict__ counter) {
  int b = blockIdx.x, t = threadIdx.x;  // 1024 x 256
  int gid = b * 256 + t;
  if (gid == 0) { *loss_accum = 0.f; *counter = 0; }
  float v = protos[b * 256 + t];
  protosb[b * 256 + t] = f2bf(v);
  float s = v * v;
  for (int off = 32; off; off >>= 1) s += __shfl_xor(s, off, 64);
  __shared__ float red[4];
  if ((t & 63) == 0) red[t >> 6] = s;
  __syncthreads();
  if (t == 0) pnorm[b] = red[0] + red[1] + red[2] + red[3];
  if (gid < 32768) w1b[gid] = f2bf(W1[gid]);
  else if (gid < 49152) w2b[gid - 32768] = f2bf(W2[gid - 32768]);
  else if (gid < 114688) wmub[gid - 49152] = f2bf(Wmu[gid - 49152]);
}

// ---------------- fused main kernel ----------------
__global__ __launch_bounds__(256, 4) void vq_fused(
    const float* __restrict__ x, const float* __restrict__ b1,
    const float* __restrict__ b2, const float* __restrict__ bmu,
    const float* __restrict__ protos, const u16* __restrict__ w1b,
    const u16* __restrict__ w2b, const u16* __restrict__ wmub,
    const u16* __restrict__ protosb, const float* __restrict__ pnorm,
    float* __restrict__ out, float* __restrict__ loss_accum,
    int* __restrict__ counter) {
  __shared__ uint4 smem4[2560];  // 40960 B
  u16* sm = (u16*)smem4;
  // scratch (post-barrier use only; overlaps h1 slices which die pre-barrier)
  float* wv = (float*)sm;                 // [4][64] bytes [0,1024)
  int* wi = (int*)(sm + 512);             // [4][64] bytes [1024,2048)
  int* idxs = (int*)(sm + 1024);          // [64]    bytes [2048,2304)
  float* lpart = (float*)(sm + 1152);     // [4]     bytes [2304,2320)
  u16* mid = sm + 4096;                   // [64][256] bf16, bytes [8192,40960)

  const int tid = threadIdx.x;
  const int wave = tid >> 6;
  const int lane = tid & 63;
  const int quad = lane >> 4;
  const int l15 = lane & 15;
  const long rowbase = (long)blockIdx.x * 64;
  u16* h1sl = sm + wave * 1024;           // [16][64] private slice

  // ===== G1: h1 = relu(x @ W1^T + b1); wave owns rows wave*16..+16 =====
  f32x4 acc1[4];
  for (int nt = 0; nt < 4; nt++) acc1[nt] = (f32x4){0.f, 0.f, 0.f, 0.f};
  {
    const float* xp = x + (rowbase + wave * 16 + l15) * 512 + quad * 8;
    const u16* w1p = w1b + l15 * 512 + quad * 8;
#pragma unroll 4
    for (int ks = 0; ks < 16; ks++) {
      f32x4 v0 = *(const f32x4*)(xp + ks * 32);
      f32x4 v1 = *(const f32x4*)(xp + ks * 32 + 4);
      u16x8 a = cvt8(v0, v1);
#pragma unroll
      for (int nt = 0; nt < 4; nt++)
        acc1[nt] = mfma16(a, *(const u16x8*)(w1p + nt * 8192 + ks * 32), acc1[nt]);
    }
#pragma unroll
    for (int nt = 0; nt < 4; nt++) {
      float bias = b1[nt * 16 + l15];
#pragma unroll
      for (int r = 0; r < 4; r++) {
        float v = acc1[nt][r] + bias;
        v = v > 0.f ? v : 0.f;
        h1sl[swh1(quad * 4 + r, nt * 16 + l15)] = f2bf(v);  // C-layout -> LDS
      }
    }
  }

  // ===== G2: h2 = relu(h1 @ W2^T + b2); same rows, all 256 cols =====
  {
    u16x8 afh0 = *(const u16x8*)(h1sl + swh1(l15, quad * 8));
    u16x8 afh1 = *(const u16x8*)(h1sl + swh1(l15, 32 + quad * 8));
    const u16* w2p = w2b + l15 * 64 + quad * 8;
    int mrow = wave * 16 + quad * 4;
#pragma unroll 4
    for (int nt = 0; nt < 16; nt++) {
      u16x8 bf0 = *(const u16x8*)(w2p + nt * 1024);
      u16x8 bf1 = *(const u16x8*)(w2p + nt * 1024 + 32);
      f32x4 acc = (f32x4){0.f, 0.f, 0.f, 0.f};
      acc = mfma16(afh0, bf0, acc);
      acc = mfma16(afh1, bf1, acc);
      float bias = b2[nt * 16 + l15];
#pragma unroll
      for (int r = 0; r < 4; r++) {
        float v = acc[r] + bias;
        v = v > 0.f ? v : 0.f;
        mid[swm(mrow + r, nt * 16 + l15)] = f2bf(v);
      }
    }
  }

  // ===== G3: lat = h2 @ Wmu^T + bmu (no relu); A-frags = whole own h2 tile =====
  {
    u16x8 af3[8];
#pragma unroll
    for (int s = 0; s < 8; s++)
      af3[s] = *(const u16x8*)(mid + swm(wave * 16 + l15, s * 32 + quad * 8));
    const u16* wmp = wmub + l15 * 256 + quad * 8;
    int mrow = wave * 16 + quad * 4;
    for (int ntp = 0; ntp < 8; ntp++) {
      int ntA = ntp * 2, ntB = ntA + 1;
      u16x8 bfA[8], bfB[8];
#pragma unroll
      for (int s = 0; s < 8; s++) {
        bfA[s] = *(const u16x8*)(wmp + ntA * 4096 + s * 32);
        bfB[s] = *(const u16x8*)(wmp + ntB * 4096 + s * 32);
      }
      f32x4 aA = (f32x4){0.f, 0.f, 0.f, 0.f}, aB = (f32x4){0.f, 0.f, 0.f, 0.f};
#pragma unroll
      for (int s = 0; s < 8; s++) {
        aA = mfma16(af3[s], bfA[s], aA);
        aB = mfma16(af3[s], bfB[s], aB);
      }
      float biA = bmu[ntA * 16 + l15], biB = bmu[ntB * 16 + l15];
#pragma unroll
      for (int r = 0; r < 4; r++) {
        mid[swm(mrow + r, ntA * 16 + l15)] = f2bf(aA[r] + biA);
        mid[swm(mrow + r, ntB * 16 + l15)] = f2bf(aB[r] + biB);
      }
    }
  }
  __syncthreads();  // B1: mid = full 64x256 lat tile

  // ===== G4: scores vs 256 owned protos; 2 passes x 32 rows, A-frags resident =====
  for (int mp = 0; mp < 2; mp++) {
    u16x8 af4[2][8];
#pragma unroll
    for (int mt2 = 0; mt2 < 2; mt2++)
#pragma unroll
      for (int s = 0; s < 8; s++)
        af4[mt2][s] = *(const u16x8*)(mid + swm(mp * 32 + mt2 * 16 + l15,
                                                s * 32 + quad * 8));
    float mv[8];
    int mi[8];
#pragma unroll
    for (int ii = 0; ii < 8; ii++) { mv[ii] = 3.4e38f; mi[ii] = 0; }
    const u16* pb = protosb + (wave * 256 + l15) * 256 + quad * 8;
    for (int g = 0; g < 8; g++) {
#pragma unroll
      for (int tt = 0; tt < 2; tt++) {
        int pcol = wave * 256 + g * 32 + tt * 16 + l15;
        float pn = pnorm[pcol];
        f32x4 acc[2];
        acc[0] = (f32x4){0.f, 0.f, 0.f, 0.f};
        acc[1] = (f32x4){0.f, 0.f, 0.f, 0.f};
#pragma unroll
        for (int sh = 0; sh < 2; sh++) {
          u16x8 bp[4];
#pragma unroll
          for (int s4 = 0; s4 < 4; s4++)
            bp[s4] = *(const u16x8*)(pb + (g * 32 + tt * 16) * 256 +
                                     (sh * 4 + s4) * 32);
#pragma unroll
          for (int mt2 = 0; mt2 < 2; mt2++)
#pragma unroll
            for (int s4 = 0; s4 < 4; s4++)
              acc[mt2] = mfma16(af4[mt2][sh * 4 + s4], bp[s4], acc[mt2]);
        }
#pragma unroll
        for (int mt2 = 0; mt2 < 2; mt2++)
#pragma unroll
          for (int r = 0; r < 4; r++) {
            float d = fmaf(-2.f, acc[mt2][r], pn);  // ||lat||^2 dropped
            int ii = mt2 * 4 + r;
            bool lt = d < mv[ii];
            mv[ii] = lt ? d : mv[ii];
            mi[ii] = lt ? pcol : mi[ii];
          }
      }
    }
    // argmin reduce across the 16 l15 lanes (first-index tie rule)
    for (int off = 1; off < 16; off <<= 1)
#pragma unroll
      for (int ii = 0; ii < 8; ii++) {
        float ov = __shfl_xor(mv[ii], off, 64);
        int oi = __shfl_xor(mi[ii], off, 64);
        if (ov < mv[ii] || (ov == mv[ii] && oi < mi[ii])) { mv[ii] = ov; mi[ii] = oi; }
      }
    if (l15 == 0)
#pragma unroll
      for (int mt2 = 0; mt2 < 2; mt2++)
#pragma unroll
        for (int r = 0; r < 4; r++) {
          int row = mp * 32 + mt2 * 16 + quad * 4 + r;
          wv[wave * 64 + row] = mv[mt2 * 4 + r];
          wi[wave * 64 + row] = mi[mt2 * 4 + r];
        }
  }
  __syncthreads();  // B2

  if (tid < 64) {  // merge the 4 wave-local argmins per row
    float bv = wv[tid];
    int bi = wi[tid];
#pragma unroll
    for (int w = 1; w < 4; w++) {
      float v = wv[w * 64 + tid];
      int i2 = wi[w * 64 + tid];
      if (v < bv || (v == bv && i2 < bi)) { bv = v; bi = i2; }
    }
    idxs[tid] = bi;
  }
  __syncthreads();  // B3

  // ===== epilogue: out = protos[idx] (exact f32), loss += (q - lat_bf16)^2 =====
  {
    int row = tid >> 2, seg = tid & 3;
    int idx = idxs[row];
    const float* qrow = protos + (size_t)idx * 256;
    float* orow = out + (size_t)(rowbase + row) * 256;
    float lsum = 0.f;
#pragma unroll 4
    for (int j = 0; j < 16; j++) {
      int c = (seg + j * 4) * 4;
      f32x4 q = *(const f32x4*)(qrow + c);
      u16x4 lb = *(const u16x4*)(mid + swm(row, c));
      float d0 = q[0] - bf2f(lb[0]);
      float d1 = q[1] - bf2f(lb[1]);
      float d2 = q[2] - bf2f(lb[2]);
      float d3 = q[3] - bf2f(lb[3]);
      lsum += d0 * d0 + d1 * d1 + d2 * d2 + d3 * d3;
      *(f32x4*)(orow + c) = q;
    }
    for (int off = 32; off; off >>= 1) lsum += __shfl_xor(lsum, off, 64);
    if (lane == 0) lpart[wave] = lsum;
  }
  __syncthreads();  // B4
  if (tid == 0) {
    float tot = lpart[0] + lpart[1] + lpart[2] + lpart[3];
    atomicAdd(loss_accum, tot);
    __threadfence();
    int c = atomicAdd(counter, 1);
    if (c == NBLK - 1) {  // last block finalizes (all loss-adds fenced before)
      float full = atomicAdd(loss_accum, 0.f);
      out[(size_t)N_ROWS * 256] = full * (1.25f / ((float)N_ROWS * 256.f));
      out[(size_t)N_ROWS * 256 + 1] = 0.f;  // capacity (int32 0 bits)
    }
  }
}

extern "C" void kernel_launch(void* const* d_in, const int* in_sizes, int n_in,
                              void* d_out, int out_size, void* d_ws, size_t ws_size,
                              hipStream_t stream) {
  const float* x = (const float*)d_in[0];
  const float* W1 = (const float*)d_in[1];
  const float* b1 = (const float*)d_in[2];
  const float* W2 = (const float*)d_in[3];
  const float* b2 = (const float*)d_in[4];
  const float* Wmu = (const float*)d_in[5];
  const float* bmu = (const float*)d_in[6];
  const float* protos = (const float*)d_in[7];
  char* ws = (char*)d_ws;
  u16* protosb = (u16*)ws;                 // 512 KB
  u16* w1b = (u16*)(ws + 524288);          // 64 KB
  u16* w2b = (u16*)(ws + 589824);          // 32 KB
  u16* wmub = (u16*)(ws + 622592);         // 128 KB
  float* pnorm = (float*)(ws + 753664);    // 4 KB
  float* loss = (float*)(ws + 757760);     // 4 B
  int* counter = (int*)(ws + 757764);      // 4 B
  float* out = (float*)d_out;

  prep<<<dim3(1024), dim3(256), 0, stream>>>(W1, W2, Wmu, protos, w1b, w2b, wmub,
                                             protosb, pnorm, loss, counter);
  vq_fused<<<dim3(NBLK), dim3(256), 0, stream>>>(x, b1, b2, bmu, protos, w1b, w2b,
                                                 wmub, protosb, pnorm, out, loss,
                                                 counter);
}